// Round 1
// baseline (84.489 us; speedup 1.0000x reference)
//
#include <hip/hip_runtime.h>
#include <math.h>

// Chamfer distance: B=16, N=M=2048, D=3, fp32.
// loss = sum_i min_j d(x_i,y_j) + sum_j min_i d(x_i,y_j)
// d = xx + (yy - 2 x.y); min_j(xx + s_j) = xx + min_j s_j  -> 4 VALU/pair.

#define BATCH 16
#define NPTS  2048
#define TILE  256

__global__ void zero_out_kernel(float* out) { out[0] = 0.0f; }

__global__ __launch_bounds__(256) void chamfer_kernel(
    const float* __restrict__ preds,
    const float* __restrict__ tgts,
    float* __restrict__ out)
{
    __shared__ float4 q[NPTS];          // opposing set: (y0,y1,y2,|y|^2) -- 32 KB
    __shared__ float  wsum[4];

    const int bid  = blockIdx.x;
    const int dir  = bid & 1;           // 0: min over targets for each pred; 1: reverse
    const int rest = bid >> 1;          // 0..127
    const int b    = rest >> 3;         // 0..15
    const int tile = rest & 7;          // 0..7

    const float* src = (dir ? tgts : preds) + (size_t)b * NPTS * 3;  // points we minimize FOR
    const float* opp = (dir ? preds : tgts) + (size_t)b * NPTS * 3;  // the candidate set

    // Stage opposing set into LDS with squared norm in .w
    for (int j = threadIdx.x; j < NPTS; j += blockDim.x) {
        float y0 = opp[3 * j + 0];
        float y1 = opp[3 * j + 1];
        float y2 = opp[3 * j + 2];
        q[j] = make_float4(y0, y1, y2, y0 * y0 + y1 * y1 + y2 * y2);
    }
    __syncthreads();

    // Each thread owns one source point
    const int i = tile * TILE + threadIdx.x;
    float p0 = src[3 * i + 0];
    float p1 = src[3 * i + 1];
    float p2 = src[3 * i + 2];
    float xx = p0 * p0 + p1 * p1 + p2 * p2;
    float n0 = -2.0f * p0, n1 = -2.0f * p1, n2 = -2.0f * p2;

    float m0 = INFINITY, m1 = INFINITY;
    #pragma unroll 8
    for (int j = 0; j < NPTS; j += 2) {
        float4 qa = q[j];
        float4 qb = q[j + 1];
        float sa = fmaf(n0, qa.x, fmaf(n1, qa.y, fmaf(n2, qa.z, qa.w)));
        float sb = fmaf(n0, qb.x, fmaf(n1, qb.y, fmaf(n2, qb.z, qb.w)));
        m0 = fminf(m0, sa);
        m1 = fminf(m1, sb);
    }
    float val = xx + fminf(m0, m1);   // this point's nearest-neighbor squared distance

    // Block-level sum reduction: wave shuffle then cross-wave via LDS
    #pragma unroll
    for (int off = 32; off > 0; off >>= 1)
        val += __shfl_down(val, off, 64);

    const int lane = threadIdx.x & 63;
    const int wid  = threadIdx.x >> 6;
    if (lane == 0) wsum[wid] = val;
    __syncthreads();
    if (threadIdx.x == 0)
        atomicAdd(out, wsum[0] + wsum[1] + wsum[2] + wsum[3]);
}

extern "C" void kernel_launch(void* const* d_in, const int* in_sizes, int n_in,
                              void* d_out, int out_size, void* d_ws, size_t ws_size,
                              hipStream_t stream) {
    const float* preds = (const float*)d_in[0];
    const float* tgts  = (const float*)d_in[1];
    float* out = (float*)d_out;

    zero_out_kernel<<<1, 1, 0, stream>>>(out);

    // 2 directions x 16 batches x 8 tiles = 256 blocks (1 per CU)
    chamfer_kernel<<<256, 256, 0, stream>>>(preds, tgts, out);
}

// Round 2
// 72.830 us; speedup vs baseline: 1.1601x; 1.1601x over previous
//
#include <hip/hip_runtime.h>
#include <math.h>

// Chamfer distance: B=16, N=M=2048, D=3, fp32.
// Stage 1: per (dir,batch,slice) block computes partial minima of
//          s_j = |y_j|^2 - 2 x.y_j over a 128-point opposing slice,
//          for all 2048 source points (8 per thread -> 32 VALU per LDS read).
// Stage 2: min over 16 slices, add |x|^2, block-sum, atomicAdd.

#define BATCH   16
#define NPTS    2048
#define KSLICE  16
#define SLICE   128          // NPTS / KSLICE
#define SPT     8            // src points per thread

__global__ void zero_out_kernel(float* out) { out[0] = 0.0f; }

__global__ __launch_bounds__(256) void chamfer_partial(
    const float* __restrict__ preds,
    const float* __restrict__ tgts,
    float* __restrict__ partial)
{
    __shared__ float4 q[SLICE];   // 2 KB

    const int bid   = blockIdx.x;     // 0..511
    const int combo = bid & 31;       // dir*16 + b
    const int slice = bid >> 5;       // 0..15
    const int dir   = combo >> 4;
    const int b     = combo & 15;

    const float* src = (dir ? tgts : preds) + (size_t)b * NPTS * 3;
    const float* opp = (dir ? preds : tgts) + (size_t)b * NPTS * 3;

    // Stage opposing slice into LDS with |y|^2 packed in .w
    if (threadIdx.x < SLICE) {
        const int jj = slice * SLICE + threadIdx.x;
        const float y0 = opp[3 * jj + 0];
        const float y1 = opp[3 * jj + 1];
        const float y2 = opp[3 * jj + 2];
        q[threadIdx.x] = make_float4(y0, y1, y2, y0 * y0 + y1 * y1 + y2 * y2);
    }

    // Each thread owns 8 source points (stride 256 for coalesced stores)
    float n0[SPT], n1[SPT], n2[SPT], m[SPT];
    #pragma unroll
    for (int k = 0; k < SPT; k++) {
        const int i = threadIdx.x + 256 * k;
        n0[k] = -2.0f * src[3 * i + 0];
        n1[k] = -2.0f * src[3 * i + 1];
        n2[k] = -2.0f * src[3 * i + 2];
        m[k]  = INFINITY;
    }
    __syncthreads();

    #pragma unroll 2
    for (int j = 0; j < SLICE; j++) {
        const float4 Q = q[j];
        #pragma unroll
        for (int k = 0; k < SPT; k++) {
            const float s = fmaf(n0[k], Q.x, fmaf(n1[k], Q.y, fmaf(n2[k], Q.z, Q.w)));
            m[k] = fminf(m[k], s);
        }
    }

    float* pp = partial + ((size_t)combo * KSLICE + slice) * NPTS;
    #pragma unroll
    for (int k = 0; k < SPT; k++)
        pp[threadIdx.x + 256 * k] = m[k];
}

__global__ __launch_bounds__(256) void chamfer_reduce(
    const float* __restrict__ preds,
    const float* __restrict__ tgts,
    const float* __restrict__ partial,
    float* __restrict__ out)
{
    __shared__ float wsum[4];

    const int g     = blockIdx.x * 256 + threadIdx.x;   // 0..65535
    const int combo = g >> 11;
    const int i     = g & (NPTS - 1);
    const int dir   = combo >> 4;
    const int b     = combo & 15;

    const float* src = (dir ? tgts : preds) + (size_t)b * NPTS * 3;
    const float x0 = src[3 * i + 0];
    const float x1 = src[3 * i + 1];
    const float x2 = src[3 * i + 2];
    const float xx = x0 * x0 + x1 * x1 + x2 * x2;

    const float* pp = partial + (size_t)combo * KSLICE * NPTS + i;
    float mn = pp[0];
    #pragma unroll
    for (int s = 1; s < KSLICE; s++)
        mn = fminf(mn, pp[(size_t)s * NPTS]);

    float val = xx + mn;

    #pragma unroll
    for (int off = 32; off > 0; off >>= 1)
        val += __shfl_down(val, off, 64);

    const int lane = threadIdx.x & 63;
    const int wid  = threadIdx.x >> 6;
    if (lane == 0) wsum[wid] = val;
    __syncthreads();
    if (threadIdx.x == 0)
        atomicAdd(out, wsum[0] + wsum[1] + wsum[2] + wsum[3]);
}

extern "C" void kernel_launch(void* const* d_in, const int* in_sizes, int n_in,
                              void* d_out, int out_size, void* d_ws, size_t ws_size,
                              hipStream_t stream) {
    const float* preds = (const float*)d_in[0];
    const float* tgts  = (const float*)d_in[1];
    float* out     = (float*)d_out;
    float* partial = (float*)d_ws;   // 32 combos x 16 slices x 2048 = 4 MB

    zero_out_kernel<<<1, 1, 0, stream>>>(out);
    chamfer_partial<<<2 * BATCH * KSLICE, 256, 0, stream>>>(preds, tgts, partial);
    chamfer_reduce<<<(2 * BATCH * NPTS) / 256, 256, 0, stream>>>(preds, tgts, partial, out);
}